// Round 1
// baseline (343.716 us; speedup 1.0000x reference)
//
#include <hip/hip_runtime.h>
#include <hip/hip_bf16.h>
#include <stdint.h>

// ---------------------------------------------------------------------------
// SelfAttention block: out = (attn(rope(rms(xWq)), rope(rms(xWk)), xWv)) Wo
// B=2, N=2048, D=2048, H=16, HD=128.  All GEMMs + attention in bf16 MFMA.
// ---------------------------------------------------------------------------

typedef __bf16 bf16;
typedef __bf16 bf16x8 __attribute__((ext_vector_type(8)));
typedef __bf16 bf16x4 __attribute__((ext_vector_type(4)));
typedef float  f32x4  __attribute__((ext_vector_type(4)));

#define MTOT   4096   // B*N token rows
#define DMODEL 2048
#define NSEQ   2048
#define NHEAD  16
#define HDIM   128
#define BK     64

static __device__ __forceinline__ void async_ld16(const void* g, void* l) {
  // global -> LDS direct copy, 16B per lane. LDS dest must be linear
  // (wave-uniform base + lane*16); swizzling is done on the GLOBAL source.
  void* gnc = const_cast<void*>(g);
  __builtin_amdgcn_global_load_lds((__attribute__((address_space(1))) void*)gnc,
                                   (__attribute__((address_space(3))) void*)l,
                                   16, 0, 0);
}

// ---------------------------------------------------------------------------
// f32 -> bf16 convert (vectorized: 2x float4 in, 1x 16B out per elem-group)
// ---------------------------------------------------------------------------
__global__ __launch_bounds__(256) void k_cvt(const float* __restrict__ in,
                                             bf16* __restrict__ out, int n8) {
  int stride = gridDim.x * blockDim.x;
  for (int i = blockIdx.x * blockDim.x + threadIdx.x; i < n8; i += stride) {
    const float4* p = (const float4*)(in) + 2 * (size_t)i;
    float4 a = p[0], b = p[1];
    bf16x8 o;
    o[0] = (bf16)a.x; o[1] = (bf16)a.y; o[2] = (bf16)a.z; o[3] = (bf16)a.w;
    o[4] = (bf16)b.x; o[5] = (bf16)b.y; o[6] = (bf16)b.z; o[7] = (bf16)b.w;
    *((bf16x8*)(out) + i) = o;
  }
}

// ---------------------------------------------------------------------------
// GEMM: C[m][n] = sum_k A[m][k] * W[n][k] + bias[n]
// 128x128 tile, BK=64, 4 waves (2x2), 4x4 16x16x32 frags per wave.
// LDS XOR-swizzled (chunk ^ (row&7)) via pre-swizzled global source.
// OUTMODE 0: bf16 row-major; 1: bf16 transposed (vt[b][n][s]); 2: f32 row-major
// ---------------------------------------------------------------------------
template <int OUTMODE>
static __device__ __forceinline__ void gemm_body(
    const bf16* __restrict__ A, const bf16* __restrict__ W,
    const float* __restrict__ bias, void* __restrict__ outp,
    int m0, int n0, bf16* sa, bf16* sb) {
  const int tid = threadIdx.x;
  const int lane = tid & 63;
  const int w = tid >> 6;
  const int wr = w >> 1, wc = w & 1;
  const int g = lane >> 4, r0 = lane & 15;

  f32x4 acc[4][4];
  const f32x4 vzero = {0.f, 0.f, 0.f, 0.f};
#pragma unroll
  for (int i = 0; i < 4; ++i)
#pragma unroll
    for (int j = 0; j < 4; ++j) acc[i][j] = vzero;

  const bf16* Abase = A + (size_t)m0 * DMODEL;
  const bf16* Wbase = W + (size_t)n0 * DMODEL;

  for (int kt = 0; kt < DMODEL / BK; ++kt) {
    const bf16* asrc = Abase + kt * BK;
    const bf16* bsrc = Wbase + kt * BK;
#pragma unroll
    for (int p = 0; p < 4; ++p) {   // 128x64 bf16 = 1024 16B-chunks, 256 thr
      int ch = tid + p * 256;
      int row = ch >> 3, cs = ch & 7;
      int c = cs ^ (row & 7);       // inverse-swizzled source chunk
      async_ld16(asrc + (size_t)row * DMODEL + c * 8, sa + ch * 8);
    }
#pragma unroll
    for (int p = 0; p < 4; ++p) {
      int ch = tid + p * 256;
      int row = ch >> 3, cs = ch & 7;
      int c = cs ^ (row & 7);
      async_ld16(bsrc + (size_t)row * DMODEL + c * 8, sb + ch * 8);
    }
    asm volatile("s_waitcnt vmcnt(0)" ::: "memory");
    __syncthreads();
#pragma unroll
    for (int ks = 0; ks < 2; ++ks) {
      bf16x8 af[4], bfr[4];
      int c = ks * 4 + g;
#pragma unroll
      for (int i = 0; i < 4; ++i) {
        int ra = wr * 64 + i * 16 + r0;
        af[i] = *(const bf16x8*)(sa + ra * BK + ((c ^ (ra & 7)) << 3));
        int rb = wc * 64 + i * 16 + r0;
        bfr[i] = *(const bf16x8*)(sb + rb * BK + ((c ^ (rb & 7)) << 3));
      }
#pragma unroll
      for (int i = 0; i < 4; ++i)
#pragma unroll
        for (int j = 0; j < 4; ++j)
          acc[i][j] = __builtin_amdgcn_mfma_f32_16x16x32_bf16(af[i], bfr[j],
                                                              acc[i][j], 0, 0, 0);
    }
    __syncthreads();
  }

  // epilogue: C layout col = lane&15, row = (lane>>4)*4 + r
#pragma unroll
  for (int i = 0; i < 4; ++i) {
#pragma unroll
    for (int j = 0; j < 4; ++j) {
      int mb = m0 + wr * 64 + i * 16 + g * 4;
      int n = n0 + wc * 64 + j * 16 + r0;
      float bn = bias[n];
      if (OUTMODE == 0) {
        bf16* o = (bf16*)outp;
#pragma unroll
        for (int r = 0; r < 4; ++r)
          o[(size_t)(mb + r) * DMODEL + n] = (bf16)(acc[i][j][r] + bn);
      } else if (OUTMODE == 2) {
        float* o = (float*)outp;
#pragma unroll
        for (int r = 0; r < 4; ++r)
          o[(size_t)(mb + r) * DMODEL + n] = acc[i][j][r] + bn;
      } else {  // vt[b][n][s], 4 consecutive s per lane -> 8B store
        bf16* o = (bf16*)outp;
        int bb = mb >> 11, s = mb & (NSEQ - 1);
        bf16x4 pk;
#pragma unroll
        for (int r = 0; r < 4; ++r) pk[r] = (bf16)(acc[i][j][r] + bn);
        *(bf16x4*)(o + (size_t)(bb * DMODEL + n) * NSEQ + s) = pk;
      }
    }
  }
}

__global__ __launch_bounds__(256) void k_gemm_qkv(
    const bf16* __restrict__ xb, const bf16* __restrict__ wq,
    const bf16* __restrict__ wk, const bf16* __restrict__ wv,
    const float* __restrict__ bq, const float* __restrict__ bk,
    const float* __restrict__ bv, bf16* __restrict__ q, bf16* __restrict__ k,
    bf16* __restrict__ vt) {
  __shared__ __align__(16) bf16 smem[2 * 128 * BK];
  int nb = blockIdx.x;               // 48 = 3 sections x 16 n-blocks
  int m0 = blockIdx.y * 128;
  int sec = nb >> 4;
  int n0 = (nb & 15) * 128;
  if (sec == 0)
    gemm_body<0>(xb, wq, bq, q, m0, n0, smem, smem + 128 * BK);
  else if (sec == 1)
    gemm_body<0>(xb, wk, bk, k, m0, n0, smem, smem + 128 * BK);
  else
    gemm_body<1>(xb, wv, bv, vt, m0, n0, smem, smem + 128 * BK);
}

__global__ __launch_bounds__(256) void k_gemm_out(
    const bf16* __restrict__ ab, const bf16* __restrict__ wo,
    const float* __restrict__ bo, float* __restrict__ out) {
  __shared__ __align__(16) bf16 smem[2 * 128 * BK];
  gemm_body<2>(ab, wo, bo, out, blockIdx.y * 128, blockIdx.x * 128, smem,
               smem + 128 * BK);
}

// ---------------------------------------------------------------------------
// Fused RMSNorm + RoPE, one row (2048 elems) per block, in place, bf16 io.
// blockIdx < 4096 -> q rows, else k rows.
// ---------------------------------------------------------------------------
__global__ __launch_bounds__(256) void k_norm_rope(
    bf16* __restrict__ q, bf16* __restrict__ kk, const float* __restrict__ gq,
    const float* __restrict__ gk, const float* __restrict__ freqs) {
  int bidx = blockIdx.x;
  bf16* buf = (bidx < MTOT) ? q : kk;
  const float* gw = (bidx < MTOT) ? gq : gk;
  int row = bidx & (MTOT - 1);
  int s = row & (NSEQ - 1);
  int tid = threadIdx.x;
  int i0 = tid * 8;
  bf16* ptr = buf + (size_t)row * DMODEL + i0;
  bf16x8 v = *(const bf16x8*)ptr;
  float x[8];
  float ssq = 0.f;
#pragma unroll
  for (int j = 0; j < 8; ++j) {
    x[j] = (float)v[j];
    ssq += x[j] * x[j];
  }
#pragma unroll
  for (int off = 1; off < 64; off <<= 1) ssq += __shfl_xor(ssq, off);
  __shared__ float part[4];
  if ((tid & 63) == 0) part[tid >> 6] = ssq;
  __syncthreads();
  float tot = part[0] + part[1] + part[2] + part[3];
  float sc = rsqrtf(tot * (1.f / DMODEL) + 1e-6f);
  float4 g0 = *(const float4*)(gw + i0);
  float4 g1 = *(const float4*)(gw + i0 + 4);
  float y[8];
  y[0] = x[0] * sc * g0.x; y[1] = x[1] * sc * g0.y;
  y[2] = x[2] * sc * g0.z; y[3] = x[3] * sc * g0.w;
  y[4] = x[4] * sc * g1.x; y[5] = x[5] * sc * g1.y;
  y[6] = x[6] * sc * g1.z; y[7] = x[7] * sc * g1.w;
  int dl = i0 & (HDIM - 1);  // even -> freq base = s*128 + dl
  const float* fp = freqs + (size_t)s * HDIM + dl;
  float4 f0 = *(const float4*)fp;
  float4 f1 = *(const float4*)(fp + 4);
  bf16x8 out;
  out[0] = (bf16)(y[0] * f0.x - y[1] * f0.y);
  out[1] = (bf16)(y[0] * f0.y + y[1] * f0.x);
  out[2] = (bf16)(y[2] * f0.z - y[3] * f0.w);
  out[3] = (bf16)(y[2] * f0.w + y[3] * f0.z);
  out[4] = (bf16)(y[4] * f1.x - y[5] * f1.y);
  out[5] = (bf16)(y[4] * f1.y + y[5] * f1.x);
  out[6] = (bf16)(y[6] * f1.z - y[7] * f1.w);
  out[7] = (bf16)(y[6] * f1.w + y[7] * f1.z);
  *(bf16x8*)ptr = out;
}

// ---------------------------------------------------------------------------
// Flash attention. grid (16 qtiles, 32 bh). 512 thr = 8 waves, 16 q-rows/wave.
// K staged [64][128] (XOR-swz), V staged from pre-transposed vt as [128][64]
// (XOR-swz). P bounced via padded per-wave LDS [16][72] into A-frag layout.
// ---------------------------------------------------------------------------
__global__ __launch_bounds__(512) void k_attn(const bf16* __restrict__ q,
                                              const bf16* __restrict__ k,
                                              const bf16* __restrict__ vt,
                                              bf16* __restrict__ o) {
  __shared__ __align__(16) bf16 sk[64 * 128];
  __shared__ __align__(16) bf16 sv[128 * 64];
  __shared__ __align__(16) bf16 sp[8 * 16 * 72];
  const int qt = blockIdx.x;
  const int bh = blockIdx.y;
  const int bb = bh >> 4, h = bh & 15;
  const int tid = threadIdx.x;
  const int lane = tid & 63, w = tid >> 6;
  const int g = lane >> 4, r0 = lane & 15;
  const float scale = 0.08838834764831845f;  // 1/sqrt(128)

  bf16x8 qf[4];
  {
    const bf16* qbase =
        q + (size_t)(bb * NSEQ + qt * 128 + w * 16 + r0) * DMODEL + h * HDIM;
#pragma unroll
    for (int ds = 0; ds < 4; ++ds)
      qf[ds] = *(const bf16x8*)(qbase + ds * 32 + g * 8);
  }
  f32x4 oacc[8];
  const f32x4 vzero = {0.f, 0.f, 0.f, 0.f};
#pragma unroll
  for (int dt = 0; dt < 8; ++dt) oacc[dt] = vzero;
  float mrow[4], lrow[4];
#pragma unroll
  for (int r = 0; r < 4; ++r) {
    mrow[r] = -3.0e38f;
    lrow[r] = 0.f;
  }

  const bf16* kbase = k + (size_t)(bb * NSEQ) * DMODEL + h * HDIM;
  const bf16* vbase = vt + (size_t)(bb * DMODEL + h * HDIM) * NSEQ;
  bf16* spw = sp + w * (16 * 72);

  for (int t = 0; t < NSEQ / 64; ++t) {
    int k0 = t * 64;
#pragma unroll
    for (int p = 0; p < 2; ++p) {  // K tile: 64 rows x 16 chunks
      int ch = tid + p * 512;
      int row = ch >> 4, cs = ch & 15;
      int c = cs ^ (row & 7);
      async_ld16(kbase + (size_t)(k0 + row) * DMODEL + c * 8, sk + ch * 8);
    }
#pragma unroll
    for (int p = 0; p < 2; ++p) {  // V tile: 128 d-rows x 8 chunks
      int ch = tid + p * 512;
      int row = ch >> 3, cs = ch & 7;
      int c = cs ^ (row & 7);
      async_ld16(vbase + (size_t)row * NSEQ + k0 + c * 8, sv + ch * 8);
    }
    asm volatile("s_waitcnt vmcnt(0)" ::: "memory");
    __syncthreads();

    // S = Q K^T  (16 q-rows x 64 keys per wave)
    f32x4 sacc[4];
#pragma unroll
    for (int kkt = 0; kkt < 4; ++kkt) sacc[kkt] = vzero;
#pragma unroll
    for (int kkt = 0; kkt < 4; ++kkt) {
      int rk = kkt * 16 + r0;
#pragma unroll
      for (int ds = 0; ds < 4; ++ds) {
        int c = ds * 4 + g;
        bf16x8 kf = *(const bf16x8*)(sk + rk * 128 + ((c ^ (rk & 7)) << 3));
        sacc[kkt] =
            __builtin_amdgcn_mfma_f32_16x16x32_bf16(qf[ds], kf, sacc[kkt], 0, 0, 0);
      }
    }
    // online softmax (per q-row stats live in 16-lane groups)
    float pm[4];
#pragma unroll
    for (int r = 0; r < 4; ++r)
      pm[r] = fmaxf(fmaxf(sacc[0][r], sacc[1][r]), fmaxf(sacc[2][r], sacc[3][r]));
#pragma unroll
    for (int off = 1; off < 16; off <<= 1) {
#pragma unroll
      for (int r = 0; r < 4; ++r) pm[r] = fmaxf(pm[r], __shfl_xor(pm[r], off));
    }
    float alpha[4], rs[4];
#pragma unroll
    for (int r = 0; r < 4; ++r) {
      float mn = fmaxf(mrow[r], pm[r] * scale);
      alpha[r] = __expf(mrow[r] - mn);
      mrow[r] = mn;
      rs[r] = 0.f;
    }
#pragma unroll
    for (int kkt = 0; kkt < 4; ++kkt) {
#pragma unroll
      for (int r = 0; r < 4; ++r) {
        float pv = __expf(sacc[kkt][r] * scale - mrow[r]);
        rs[r] += pv;
        spw[(g * 4 + r) * 72 + kkt * 16 + r0] = (bf16)pv;
      }
    }
#pragma unroll
    for (int off = 1; off < 16; off <<= 1) {
#pragma unroll
      for (int r = 0; r < 4; ++r) rs[r] += __shfl_xor(rs[r], off);
    }
#pragma unroll
    for (int r = 0; r < 4; ++r) lrow[r] = lrow[r] * alpha[r] + rs[r];
#pragma unroll
    for (int dt = 0; dt < 8; ++dt) {
#pragma unroll
      for (int r = 0; r < 4; ++r) oacc[dt][r] *= alpha[r];
    }
    // O += P V
#pragma unroll
    for (int ks = 0; ks < 2; ++ks) {
      bf16x8 pf = *(const bf16x8*)(spw + r0 * 72 + ks * 32 + g * 8);
#pragma unroll
      for (int dt = 0; dt < 8; ++dt) {
        int rv = dt * 16 + r0;
        int c = ks * 4 + g;
        bf16x8 vf = *(const bf16x8*)(sv + rv * 64 + ((c ^ (rv & 7)) << 3));
        oacc[dt] = __builtin_amdgcn_mfma_f32_16x16x32_bf16(pf, vf, oacc[dt], 0, 0, 0);
      }
    }
    __syncthreads();
  }
  float rl[4];
#pragma unroll
  for (int r = 0; r < 4; ++r) rl[r] = 1.f / lrow[r];
  bf16* obase =
      o + (size_t)(bb * NSEQ + qt * 128 + w * 16 + g * 4) * DMODEL + h * HDIM;
#pragma unroll
  for (int dt = 0; dt < 8; ++dt)
#pragma unroll
    for (int r = 0; r < 4; ++r)
      obase[(size_t)r * DMODEL + dt * 16 + r0] = (bf16)(oacc[dt][r] * rl[r]);
}

// ---------------------------------------------------------------------------
// Workspace layout (bytes):
//   0         xb  (16.78M) -> reused as attn-out after gemm_qkv
//   16.78M    qb  (16.78M)
//   33.55M    kb  (16.78M)
//   50.33M    vtb (16.78M)
//   67.11M    wqb (8.39M)  -> reused as wob after gemm_qkv
//   75.50M    wkb (8.39M)
//   83.89M    wvb (8.39M)   total 92.27 MB
// ---------------------------------------------------------------------------
extern "C" void kernel_launch(void* const* d_in, const int* in_sizes, int n_in,
                              void* d_out, int out_size, void* d_ws,
                              size_t ws_size, hipStream_t stream) {
  (void)in_sizes; (void)n_in; (void)out_size; (void)ws_size;
  const float* x = (const float*)d_in[0];
  const float* freqs = (const float*)d_in[1];
  const float* wq = (const float*)d_in[2];
  const float* bq = (const float*)d_in[3];
  const float* wk = (const float*)d_in[4];
  const float* bk = (const float*)d_in[5];
  const float* wv = (const float*)d_in[6];
  const float* bv = (const float*)d_in[7];
  const float* wo = (const float*)d_in[8];
  const float* bo = (const float*)d_in[9];
  const float* gq = (const float*)d_in[10];
  const float* gk = (const float*)d_in[11];

  char* ws = (char*)d_ws;
  const size_t SZ_TOK = (size_t)MTOT * DMODEL * sizeof(bf16);  // 16.78 MB
  const size_t SZ_W = (size_t)DMODEL * DMODEL * sizeof(bf16);  // 8.39 MB
  bf16* xb = (bf16*)ws;                       // also attn-out buffer later
  bf16* qb = (bf16*)(ws + SZ_TOK);
  bf16* kb = (bf16*)(ws + 2 * SZ_TOK);
  bf16* vtb = (bf16*)(ws + 3 * SZ_TOK);
  bf16* wqb = (bf16*)(ws + 4 * SZ_TOK);       // also wo-bf16 later
  bf16* wkb = (bf16*)(ws + 4 * SZ_TOK + SZ_W);
  bf16* wvb = (bf16*)(ws + 4 * SZ_TOK + 2 * SZ_W);

  // converts
  k_cvt<<<2048, 256, 0, stream>>>(x, xb, (MTOT * DMODEL) / 8);
  k_cvt<<<1024, 256, 0, stream>>>(wq, wqb, (DMODEL * DMODEL) / 8);
  k_cvt<<<1024, 256, 0, stream>>>(wk, wkb, (DMODEL * DMODEL) / 8);
  k_cvt<<<1024, 256, 0, stream>>>(wv, wvb, (DMODEL * DMODEL) / 8);

  // QKV projections (+bias); v written transposed
  k_gemm_qkv<<<dim3(48, 32), 256, 0, stream>>>(xb, wqb, wkb, wvb, bq, bk, bv,
                                               qb, kb, vtb);
  // wo convert reuses wqb space (wq dead after gemm_qkv)
  k_cvt<<<1024, 256, 0, stream>>>(wo, wqb, (DMODEL * DMODEL) / 8);

  // rmsnorm + rope on q and k (in place)
  k_norm_rope<<<2 * MTOT, 256, 0, stream>>>(qb, kb, gq, gk, freqs);

  // flash attention -> xb (reused as attn-out, row-major [4096, 2048] bf16)
  k_attn<<<dim3(16, 32), 512, 0, stream>>>(qb, kb, vtb, xb);

  // output projection -> f32 d_out
  k_gemm_out<<<dim3(16, 32), 256, 0, stream>>>(xb, wqb, bo, (float*)d_out);
}

// Round 2
// 311.731 us; speedup vs baseline: 1.1026x; 1.1026x over previous
//
#include <hip/hip_runtime.h>
#include <hip/hip_bf16.h>
#include <stdint.h>

// ---------------------------------------------------------------------------
// SelfAttention block: out = (attn(rope(rms(xWq)), rope(rms(xWk)), xWv)) Wo
// B=2, N=2048, D=2048, H=16, HD=128.  All GEMMs + attention in bf16 MFMA.
// ---------------------------------------------------------------------------

typedef __bf16 bf16;
typedef __bf16 bf16x8 __attribute__((ext_vector_type(8)));
typedef __bf16 bf16x4 __attribute__((ext_vector_type(4)));
typedef float  f32x4  __attribute__((ext_vector_type(4)));

#define MTOT   4096   // B*N token rows
#define DMODEL 2048
#define NSEQ   2048
#define NHEAD  16
#define HDIM   128
#define BK     64

static __device__ __forceinline__ void async_ld16(const void* g, void* l) {
  void* gnc = const_cast<void*>(g);
  __builtin_amdgcn_global_load_lds((__attribute__((address_space(1))) void*)gnc,
                                   (__attribute__((address_space(3))) void*)l,
                                   16, 0, 0);
}

// ---------------------------------------------------------------------------
// f32 -> bf16 convert
// ---------------------------------------------------------------------------
__global__ __launch_bounds__(256) void k_cvt(const float* __restrict__ in,
                                             bf16* __restrict__ out, int n8) {
  int stride = gridDim.x * blockDim.x;
  for (int i = blockIdx.x * blockDim.x + threadIdx.x; i < n8; i += stride) {
    const float4* p = (const float4*)(in) + 2 * (size_t)i;
    float4 a = p[0], b = p[1];
    bf16x8 o;
    o[0] = (bf16)a.x; o[1] = (bf16)a.y; o[2] = (bf16)a.z; o[3] = (bf16)a.w;
    o[4] = (bf16)b.x; o[5] = (bf16)b.y; o[6] = (bf16)b.z; o[7] = (bf16)b.w;
    *((bf16x8*)(out) + i) = o;
  }
}

// ---------------------------------------------------------------------------
// GEMM: C[m][n] = sum_k A[m][k] * W[n][k] + bias[n]   (unchanged from R1)
// ---------------------------------------------------------------------------
template <int OUTMODE>
static __device__ __forceinline__ void gemm_body(
    const bf16* __restrict__ A, const bf16* __restrict__ W,
    const float* __restrict__ bias, void* __restrict__ outp,
    int m0, int n0, bf16* sa, bf16* sb) {
  const int tid = threadIdx.x;
  const int lane = tid & 63;
  const int w = tid >> 6;
  const int wr = w >> 1, wc = w & 1;
  const int g = lane >> 4, r0 = lane & 15;

  f32x4 acc[4][4];
  const f32x4 vzero = {0.f, 0.f, 0.f, 0.f};
#pragma unroll
  for (int i = 0; i < 4; ++i)
#pragma unroll
    for (int j = 0; j < 4; ++j) acc[i][j] = vzero;

  const bf16* Abase = A + (size_t)m0 * DMODEL;
  const bf16* Wbase = W + (size_t)n0 * DMODEL;

  for (int kt = 0; kt < DMODEL / BK; ++kt) {
    const bf16* asrc = Abase + kt * BK;
    const bf16* bsrc = Wbase + kt * BK;
#pragma unroll
    for (int p = 0; p < 4; ++p) {
      int ch = tid + p * 256;
      int row = ch >> 3, cs = ch & 7;
      int c = cs ^ (row & 7);
      async_ld16(asrc + (size_t)row * DMODEL + c * 8, sa + ch * 8);
    }
#pragma unroll
    for (int p = 0; p < 4; ++p) {
      int ch = tid + p * 256;
      int row = ch >> 3, cs = ch & 7;
      int c = cs ^ (row & 7);
      async_ld16(bsrc + (size_t)row * DMODEL + c * 8, sb + ch * 8);
    }
    asm volatile("s_waitcnt vmcnt(0)" ::: "memory");
    __syncthreads();
#pragma unroll
    for (int ks = 0; ks < 2; ++ks) {
      bf16x8 af[4], bfr[4];
      int c = ks * 4 + g;
#pragma unroll
      for (int i = 0; i < 4; ++i) {
        int ra = wr * 64 + i * 16 + r0;
        af[i] = *(const bf16x8*)(sa + ra * BK + ((c ^ (ra & 7)) << 3));
        int rb = wc * 64 + i * 16 + r0;
        bfr[i] = *(const bf16x8*)(sb + rb * BK + ((c ^ (rb & 7)) << 3));
      }
#pragma unroll
      for (int i = 0; i < 4; ++i)
#pragma unroll
        for (int j = 0; j < 4; ++j)
          acc[i][j] = __builtin_amdgcn_mfma_f32_16x16x32_bf16(af[i], bfr[j],
                                                              acc[i][j], 0, 0, 0);
    }
    __syncthreads();
  }

#pragma unroll
  for (int i = 0; i < 4; ++i) {
#pragma unroll
    for (int j = 0; j < 4; ++j) {
      int mb = m0 + wr * 64 + i * 16 + g * 4;
      int n = n0 + wc * 64 + j * 16 + r0;
      float bn = bias[n];
      if (OUTMODE == 0) {
        bf16* o = (bf16*)outp;
#pragma unroll
        for (int r = 0; r < 4; ++r)
          o[(size_t)(mb + r) * DMODEL + n] = (bf16)(acc[i][j][r] + bn);
      } else if (OUTMODE == 2) {
        float* o = (float*)outp;
#pragma unroll
        for (int r = 0; r < 4; ++r)
          o[(size_t)(mb + r) * DMODEL + n] = acc[i][j][r] + bn;
      } else {
        bf16* o = (bf16*)outp;
        int bb = mb >> 11, s = mb & (NSEQ - 1);
        bf16x4 pk;
#pragma unroll
        for (int r = 0; r < 4; ++r) pk[r] = (bf16)(acc[i][j][r] + bn);
        *(bf16x4*)(o + (size_t)(bb * DMODEL + n) * NSEQ + s) = pk;
      }
    }
  }
}

__global__ __launch_bounds__(256) void k_gemm_qkv(
    const bf16* __restrict__ xb, const bf16* __restrict__ wq,
    const bf16* __restrict__ wk, const bf16* __restrict__ wv,
    const float* __restrict__ bq, const float* __restrict__ bk,
    const float* __restrict__ bv, bf16* __restrict__ q, bf16* __restrict__ k,
    bf16* __restrict__ vt) {
  __shared__ __align__(16) bf16 smem[2 * 128 * BK];
  int nb = blockIdx.x;
  int m0 = blockIdx.y * 128;
  int sec = nb >> 4;
  int n0 = (nb & 15) * 128;
  if (sec == 0)
    gemm_body<0>(xb, wq, bq, q, m0, n0, smem, smem + 128 * BK);
  else if (sec == 1)
    gemm_body<0>(xb, wk, bk, k, m0, n0, smem, smem + 128 * BK);
  else
    gemm_body<1>(xb, wv, bv, vt, m0, n0, smem, smem + 128 * BK);
}

__global__ __launch_bounds__(256) void k_gemm_out(
    const bf16* __restrict__ ab, const bf16* __restrict__ wo,
    const float* __restrict__ bo, float* __restrict__ out) {
  __shared__ __align__(16) bf16 smem[2 * 128 * BK];
  gemm_body<2>(ab, wo, bo, out, blockIdx.y * 128, blockIdx.x * 128, smem,
               smem + 128 * BK);
}

// ---------------------------------------------------------------------------
// Fused RMSNorm + RoPE (+ fold 1/sqrt(HD) into q so attn skips the scale).
// ---------------------------------------------------------------------------
__global__ __launch_bounds__(256) void k_norm_rope(
    bf16* __restrict__ q, bf16* __restrict__ kk, const float* __restrict__ gq,
    const float* __restrict__ gk, const float* __restrict__ freqs) {
  int bidx = blockIdx.x;
  bf16* buf = (bidx < MTOT) ? q : kk;
  const float* gw = (bidx < MTOT) ? gq : gk;
  float qs = (bidx < MTOT) ? 0.08838834764831845f : 1.0f;  // 1/sqrt(128)
  int row = bidx & (MTOT - 1);
  int s = row & (NSEQ - 1);
  int tid = threadIdx.x;
  int i0 = tid * 8;
  bf16* ptr = buf + (size_t)row * DMODEL + i0;
  bf16x8 v = *(const bf16x8*)ptr;
  float x[8];
  float ssq = 0.f;
#pragma unroll
  for (int j = 0; j < 8; ++j) {
    x[j] = (float)v[j];
    ssq += x[j] * x[j];
  }
#pragma unroll
  for (int off = 1; off < 64; off <<= 1) ssq += __shfl_xor(ssq, off);
  __shared__ float part[4];
  if ((tid & 63) == 0) part[tid >> 6] = ssq;
  __syncthreads();
  float tot = part[0] + part[1] + part[2] + part[3];
  float sc = rsqrtf(tot * (1.f / DMODEL) + 1e-6f) * qs;
  float4 g0 = *(const float4*)(gw + i0);
  float4 g1 = *(const float4*)(gw + i0 + 4);
  float y[8];
  y[0] = x[0] * sc * g0.x; y[1] = x[1] * sc * g0.y;
  y[2] = x[2] * sc * g0.z; y[3] = x[3] * sc * g0.w;
  y[4] = x[4] * sc * g1.x; y[5] = x[5] * sc * g1.y;
  y[6] = x[6] * sc * g1.z; y[7] = x[7] * sc * g1.w;
  int dl = i0 & (HDIM - 1);
  const float* fp = freqs + (size_t)s * HDIM + dl;
  float4 f0 = *(const float4*)fp;
  float4 f1 = *(const float4*)(fp + 4);
  bf16x8 out;
  out[0] = (bf16)(y[0] * f0.x - y[1] * f0.y);
  out[1] = (bf16)(y[0] * f0.y + y[1] * f0.x);
  out[2] = (bf16)(y[2] * f0.z - y[3] * f0.w);
  out[3] = (bf16)(y[2] * f0.w + y[3] * f0.z);
  out[4] = (bf16)(y[4] * f1.x - y[5] * f1.y);
  out[5] = (bf16)(y[4] * f1.y + y[5] * f1.x);
  out[6] = (bf16)(y[6] * f1.z - y[7] * f1.w);
  out[7] = (bf16)(y[6] * f1.w + y[7] * f1.z);
  *(bf16x8*)ptr = out;
}

// ---------------------------------------------------------------------------
// Flash attention v2: swapped QK^T (lane owns q-row r0), in-register softmax
// and P->A-frag redistribution (cvt_pk + shfl), K/V double-buffer prefetch.
// Grid: 512 1-D blocks; bid&7 = XCD slot, 4 bh per XCD for K/V L2 locality.
// LDS: 2*16KB (K) + 2*16KB (V) = 64KB -> 2 blocks/CU.
// ---------------------------------------------------------------------------
__global__ __launch_bounds__(512, 4) void k_attn(const bf16* __restrict__ q,
                                                 const bf16* __restrict__ k,
                                                 const bf16* __restrict__ vt,
                                                 bf16* __restrict__ o) {
  __shared__ __align__(16) bf16 sk[2][64 * 128];
  __shared__ __align__(16) bf16 sv[2][128 * 64];
  const int bid = blockIdx.x;
  const int idx = bid >> 3;
  const int bh = (bid & 7) * 4 + (idx >> 4);  // 4 bh per XCD
  const int qt = idx & 15;
  const int bb = bh >> 4, h = bh & 15;
  const int tid = threadIdx.x;
  const int lane = tid & 63, w = tid >> 6;
  const int g = lane >> 4, r0 = lane & 15;

  // Q fragments (already scaled by 1/sqrt(HD))
  bf16x8 qf[4];
  {
    const bf16* qbase =
        q + (size_t)(bb * NSEQ + qt * 128 + w * 16 + r0) * DMODEL + h * HDIM;
#pragma unroll
    for (int ds = 0; ds < 4; ++ds)
      qf[ds] = *(const bf16x8*)(qbase + ds * 32 + g * 8);
  }
  f32x4 oacc[8];
  const f32x4 vzero = {0.f, 0.f, 0.f, 0.f};
#pragma unroll
  for (int dt = 0; dt < 8; ++dt) oacc[dt] = vzero;
  float m = -3.0e38f, l = 0.f;

  const bf16* kbase = k + (size_t)(bb * NSEQ) * DMODEL + h * HDIM;
  const bf16* vbase = vt + (size_t)(bb * DMODEL + h * HDIM) * NSEQ;

  const int s0lane = ((lane & 16) << 1) | r0;  // src lane for af words 0,1
  const int s1lane = s0lane | 16;              // src lane for af words 2,3
  const bool hi5 = (lane & 32) != 0;

  auto stage = [&](int t, int buf) {
    int k0 = t * 64;
#pragma unroll
    for (int p = 0; p < 2; ++p) {  // K tile: 64 rows x 16 chunks
      int ch = tid + p * 512;
      int row = ch >> 4, cs = ch & 15;
      int c = cs ^ (row & 7);
      async_ld16(kbase + (size_t)(k0 + row) * DMODEL + c * 8, &sk[buf][ch * 8]);
    }
#pragma unroll
    for (int p = 0; p < 2; ++p) {  // V tile: 128 d-rows x 8 chunks
      int ch = tid + p * 512;
      int row = ch >> 3, cs = ch & 7;
      int c = cs ^ (row & 7);
      async_ld16(vbase + (size_t)row * NSEQ + k0 + c * 8, &sv[buf][ch * 8]);
    }
  };

  stage(0, 0);
  for (int t = 0; t < NSEQ / 64; ++t) {
    const int cur = t & 1;
    asm volatile("s_waitcnt vmcnt(0)" ::: "memory");
    __syncthreads();
    if (t + 1 < NSEQ / 64) stage(t + 1, cur ^ 1);  // overlaps compute below

    // S^T = K Q^T : sacc[kkt] lane(g,r0) = S[k=16kkt+4g+r][q=r0]
    f32x4 sacc[4];
#pragma unroll
    for (int kkt = 0; kkt < 4; ++kkt) sacc[kkt] = vzero;
#pragma unroll
    for (int kkt = 0; kkt < 4; ++kkt) {
      int rk = kkt * 16 + r0;
#pragma unroll
      for (int ds = 0; ds < 4; ++ds) {
        int c = ds * 4 + g;
        bf16x8 kf = *(const bf16x8*)(&sk[cur][rk * 128 + ((c ^ (rk & 7)) << 3)]);
        sacc[kkt] =
            __builtin_amdgcn_mfma_f32_16x16x32_bf16(kf, qf[ds], sacc[kkt], 0, 0, 0);
      }
    }

    // per-lane softmax for q-row r0 (16 values here, full row via 2 shfls)
    float pm = sacc[0][0];
#pragma unroll
    for (int kkt = 0; kkt < 4; ++kkt)
#pragma unroll
      for (int r = 0; r < 4; ++r) pm = fmaxf(pm, sacc[kkt][r]);
    pm = fmaxf(pm, __shfl_xor(pm, 16));
    pm = fmaxf(pm, __shfl_xor(pm, 32));
    const int need = __any(pm > m);
    const float mu = need ? fmaxf(m, pm) : m;

    uint32_t W[4][2];  // packed bf16 P, W[kkt][h]: h=0 -> r=0,1; h=1 -> r=2,3
    float rs = 0.f;
#pragma unroll
    for (int kkt = 0; kkt < 4; ++kkt) {
      float p0 = __expf(sacc[kkt][0] - mu);
      float p1 = __expf(sacc[kkt][1] - mu);
      float p2 = __expf(sacc[kkt][2] - mu);
      float p3 = __expf(sacc[kkt][3] - mu);
      rs += (p0 + p1) + (p2 + p3);
      asm("v_cvt_pk_bf16_f32 %0, %1, %2" : "=v"(W[kkt][0]) : "v"(p0), "v"(p1));
      asm("v_cvt_pk_bf16_f32 %0, %1, %2" : "=v"(W[kkt][1]) : "v"(p2), "v"(p3));
    }
    rs += __shfl_xor(rs, 16);
    rs += __shfl_xor(rs, 32);

    if (need) {
      float alpha = __expf(m - mu);
      m = mu;
      l = l * alpha + rs;
      float a4[4];
#pragma unroll
      for (int r = 0; r < 4; ++r)
        a4[r] = __shfl(alpha, (lane & 48) | (g * 4 + r));
#pragma unroll
      for (int dt = 0; dt < 8; ++dt)
#pragma unroll
        for (int r = 0; r < 4; ++r) oacc[dt][r] *= a4[r];
    } else {
      l += rs;
    }

    // P redistribution: af[ks] lane(g,r0) = P[q=r0][k=32ks+8g+j], j=0..7
#pragma unroll
    for (int ks = 0; ks < 2; ++ks) {
      union { uint32_t u[4]; bf16x8 v; } pa;
#pragma unroll
      for (int ww = 0; ww < 4; ++ww) {
        int src = (ww < 2) ? s0lane : s1lane;
        int lo = __shfl((int)W[2 * ks][ww & 1], src);
        int hv = __shfl((int)W[2 * ks + 1][ww & 1], src);
        pa.u[ww] = hi5 ? (uint32_t)hv : (uint32_t)lo;
      }
      // O += P V for this 32-wide k-slice
#pragma unroll
      for (int dt = 0; dt < 8; ++dt) {
        int rv = dt * 16 + r0;
        int c = ks * 4 + g;
        bf16x8 vf = *(const bf16x8*)(&sv[cur][rv * 64 + ((c ^ (rv & 7)) << 3)]);
        oacc[dt] =
            __builtin_amdgcn_mfma_f32_16x16x32_bf16(pa.v, vf, oacc[dt], 0, 0, 0);
      }
    }
  }

  float rl[4];
#pragma unroll
  for (int r = 0; r < 4; ++r) {
    float lr = __shfl(l, (lane & 48) | (g * 4 + r));
    rl[r] = 1.f / lr;
  }
  bf16* obase =
      o + (size_t)(bb * NSEQ + qt * 128 + w * 16 + g * 4) * DMODEL + h * HDIM;
#pragma unroll
  for (int dt = 0; dt < 8; ++dt)
#pragma unroll
    for (int r = 0; r < 4; ++r)
      obase[(size_t)r * DMODEL + dt * 16 + r0] = (bf16)(oacc[dt][r] * rl[r]);
}

// ---------------------------------------------------------------------------
extern "C" void kernel_launch(void* const* d_in, const int* in_sizes, int n_in,
                              void* d_out, int out_size, void* d_ws,
                              size_t ws_size, hipStream_t stream) {
  (void)in_sizes; (void)n_in; (void)out_size; (void)ws_size;
  const float* x = (const float*)d_in[0];
  const float* freqs = (const float*)d_in[1];
  const float* wq = (const float*)d_in[2];
  const float* bq = (const float*)d_in[3];
  const float* wk = (const float*)d_in[4];
  const float* bk = (const float*)d_in[5];
  const float* wv = (const float*)d_in[6];
  const float* bv = (const float*)d_in[7];
  const float* wo = (const float*)d_in[8];
  const float* bo = (const float*)d_in[9];
  const float* gq = (const float*)d_in[10];
  const float* gk = (const float*)d_in[11];

  char* ws = (char*)d_ws;
  const size_t SZ_TOK = (size_t)MTOT * DMODEL * sizeof(bf16);
  const size_t SZ_W = (size_t)DMODEL * DMODEL * sizeof(bf16);
  bf16* xb = (bf16*)ws;
  bf16* qb = (bf16*)(ws + SZ_TOK);
  bf16* kb = (bf16*)(ws + 2 * SZ_TOK);
  bf16* vtb = (bf16*)(ws + 3 * SZ_TOK);
  bf16* wqb = (bf16*)(ws + 4 * SZ_TOK);
  bf16* wkb = (bf16*)(ws + 4 * SZ_TOK + SZ_W);
  bf16* wvb = (bf16*)(ws + 4 * SZ_TOK + 2 * SZ_W);

  k_cvt<<<2048, 256, 0, stream>>>(x, xb, (MTOT * DMODEL) / 8);
  k_cvt<<<1024, 256, 0, stream>>>(wq, wqb, (DMODEL * DMODEL) / 8);
  k_cvt<<<1024, 256, 0, stream>>>(wk, wkb, (DMODEL * DMODEL) / 8);
  k_cvt<<<1024, 256, 0, stream>>>(wv, wvb, (DMODEL * DMODEL) / 8);

  k_gemm_qkv<<<dim3(48, 32), 256, 0, stream>>>(xb, wqb, wkb, wvb, bq, bk, bv,
                                               qb, kb, vtb);
  k_cvt<<<1024, 256, 0, stream>>>(wo, wqb, (DMODEL * DMODEL) / 8);

  k_norm_rope<<<2 * MTOT, 256, 0, stream>>>(qb, kb, gq, gk, freqs);

  k_attn<<<512, 512, 0, stream>>>(qb, kb, vtb, xb);

  k_gemm_out<<<dim3(16, 32), 256, 0, stream>>>(xb, wqb, bo, (float*)d_out);
}